// Round 2
// baseline (11834.795 us; speedup 1.0000x reference)
//
#include <hip/hip_runtime.h>
#include <hip/hip_bf16.h>

// BasicLSTM: B=64, T=512, D=512, U=1024.  out = h_last [64][1024] f32.
// Structure: transpose weights to bf16 [N][K]; per time-chunk (sized by
// ws_size): xz = x@Wx + b (f32) then persistent 64-block recurrent kernel
// with per-step grid barrier (fence + relaxed agent atomic counter).

#define T_STEPS 512
#define BATCH   64
#define DIM     512
#define UNITS   1024
#define ZCOLS   4096

typedef float        f32x4 __attribute__((ext_vector_type(4)));
typedef unsigned int u32x4 __attribute__((ext_vector_type(4)));

__device__ __forceinline__ f32x4 mfma16x16x32_bf16(u32x4 a, u32x4 b, f32x4 c) {
    asm("v_mfma_f32_16x16x32_bf16 %0, %1, %2, %0" : "+v"(c) : "v"(a), "v"(b));
    return c;
}

__device__ __forceinline__ unsigned short f2bf(float f) {
    union { float f; unsigned u; } v; v.f = f;
    unsigned r = v.u + 0x7fffu + ((v.u >> 16) & 1u);   // RNE
    return (unsigned short)(r >> 16);
}

__device__ __forceinline__ float fsigmoid(float x) {
    return 1.0f / (1.0f + __expf(-x));
}
__device__ __forceinline__ float ftanh(float x) {
    return 1.0f - 2.0f / (__expf(2.0f * x) + 1.0f);
}

// pack 8 consecutive f32 -> 8 bf16 in a u32x4 (memory order, lo half = even)
__device__ __forceinline__ u32x4 pack8(const float* __restrict__ p) {
    float4 f0 = reinterpret_cast<const float4*>(p)[0];
    float4 f1 = reinterpret_cast<const float4*>(p)[1];
    u32x4 r;
    r.x = (unsigned)f2bf(f0.x) | ((unsigned)f2bf(f0.y) << 16);
    r.y = (unsigned)f2bf(f0.z) | ((unsigned)f2bf(f0.w) << 16);
    r.z = (unsigned)f2bf(f1.x) | ((unsigned)f2bf(f1.y) << 16);
    r.w = (unsigned)f2bf(f1.z) | ((unsigned)f2bf(f1.w) << 16);
    return r;
}

// ---------------- prep kernels ----------------

// in: f32 [K][N] row-major  ->  out: bf16 [N][K]
__global__ void k_transpose_bf16(const float* __restrict__ in, unsigned short* __restrict__ out,
                                 int K, int N) {
    __shared__ float tile[32][33];
    int n0 = blockIdx.x * 32, k0 = blockIdx.y * 32;
    int tx = threadIdx.x, ty = threadIdx.y;
    tile[ty][tx] = in[(size_t)(k0 + ty) * N + n0 + tx];
    __syncthreads();
    out[(size_t)(n0 + ty) * K + k0 + tx] = f2bf(tile[tx][ty]);
}

__global__ void k_init(unsigned int* __restrict__ hbuf_u32, float* __restrict__ cbuf,
                       unsigned int* __restrict__ cnt) {
    int i = blockIdx.x * blockDim.x + threadIdx.x;       // 131072 threads
    if (i < 65536) hbuf_u32[i] = 0u;                     // 2*64*1024 bf16
    else cbuf[i - 65536] = 0.0f;                         // 64*1024 f32
    if (i == 0) *cnt = 0u;
}

// ---------------- phase 1: xz(chunk) = x_t @ Wx + b ----------------
// grid (64, T_c): blockIdx.y = chunk-local t; 256 threads = 4 waves, wave w
// covers batches [16w,16w+16).  A read from f32 x with on-the-fly bf16 pack.
__global__ void k_xproj(const float* __restrict__ x,
                        const unsigned short* __restrict__ WxT,   // [4096][512]
                        const float* __restrict__ bias,
                        float* __restrict__ xz,                   // [T_c][64][4096]
                        int base) {
    const int tid  = threadIdx.x;
    const int lane = tid & 63;
    const int w    = tid >> 6;               // 0..3
    const int n0   = blockIdx.x * 64;
    const int t    = blockIdx.y;             // chunk-local step
    const int r16  = lane & 15;
    const int kl   = (lane >> 4) * 8;

    const float* ap = x + ((size_t)(w * 16 + r16) * T_STEPS + base + t) * DIM + kl;
    const unsigned short* bp = WxT + (size_t)(n0 + r16) * DIM + kl;

    f32x4 acc0 = {0,0,0,0}, acc1 = {0,0,0,0}, acc2 = {0,0,0,0}, acc3 = {0,0,0,0};
    asm volatile("s_nop 1" : "+v"(acc0), "+v"(acc1), "+v"(acc2), "+v"(acc3));
    #pragma unroll 2
    for (int kk = 0; kk < DIM / 32; ++kk) {
        u32x4 a  = pack8(ap + kk * 32);
        u32x4 b0 = *reinterpret_cast<const u32x4*>(bp + kk * 32);
        u32x4 b1 = *reinterpret_cast<const u32x4*>(bp + 16 * DIM + kk * 32);
        u32x4 b2 = *reinterpret_cast<const u32x4*>(bp + 32 * DIM + kk * 32);
        u32x4 b3 = *reinterpret_cast<const u32x4*>(bp + 48 * DIM + kk * 32);
        acc0 = mfma16x16x32_bf16(a, b0, acc0);
        acc1 = mfma16x16x32_bf16(a, b1, acc1);
        acc2 = mfma16x16x32_bf16(a, b2, acc2);
        acc3 = mfma16x16x32_bf16(a, b3, acc3);
    }
    asm volatile("s_nop 7\n\ts_nop 7\n\ts_nop 1" : "+v"(acc0), "+v"(acc1), "+v"(acc2), "+v"(acc3));

    const int rowq = (lane >> 4) * 4;
    #pragma unroll
    for (int j = 0; j < 4; ++j) {
        f32x4 acc = (j == 0) ? acc0 : (j == 1) ? acc1 : (j == 2) ? acc2 : acc3;
        const int col = n0 + j * 16 + r16;
        const float bv = bias[col];
        #pragma unroll
        for (int r = 0; r < 4; ++r) {
            int b = w * 16 + rowq + r;
            xz[((size_t)t * BATCH + b) * ZCOLS + col] = acc[r] + bv;
        }
    }
}

// ---------------- phase 2: recurrence ----------------
// 64 blocks x 1024 threads. Block owns 16 units (64 z-cols). Wave w: row-tile
// rt=w&3 (16 of 64 batch rows), gate ct=w>>2; full K=1024 per wave.
__global__ __launch_bounds__(1024, 1) void k_lstm(
        const float* __restrict__ xz,            // [T_c][64][4096], bias folded
        const unsigned short* __restrict__ WhT,  // [4096][1024]
        unsigned short* hbuf,                    // [2][64][1024] bf16
        float* __restrict__ cbuf,                // [64][1024] f32
        float* __restrict__ out,                 // [64][1024] f32
        unsigned int* cnt,
        int base_step, int tc, int base_round) {
    const int tid  = threadIdx.x;
    const int lane = tid & 63;
    const int w    = tid >> 6;          // 0..15
    const int rt   = w & 3;
    const int ct   = w >> 2;            // gate 0..3
    const int u0   = blockIdx.x * 16;
    const int c16  = lane & 15;
    const int kl   = (lane >> 4) * 8;

    __shared__ __align__(16) unsigned short whs[64 * 1024];  // 128 KB, XOR-swizzled
    __shared__ float zbuf[64][68];                           // 17 KB

    // stage Wh slice: 64 z-cols (cc = g*16+ui -> WhT row g*1024+u0+ui), k=1024
    for (int i = tid; i < 8192; i += 1024) {
        int cc = i >> 7, kc = i & 127;                 // kc: k-octet
        int g = cc >> 4, ui = cc & 15;
        u32x4 v = *reinterpret_cast<const u32x4*>(
            WhT + ((size_t)g * UNITS + u0 + ui) * UNITS + kc * 8);
        int lb = (cc * 2048 + kc * 16) ^ ((cc & 7) << 4);
        *reinterpret_cast<u32x4*>(reinterpret_cast<char*>(whs) + lb) = v;
    }

    const int row_g = tid >> 4;          // gate phase: batch row 0..63
    const int ui_g  = tid & 15;          //   unit within block
    float creg = cbuf[(size_t)row_g * UNITS + u0 + ui_g];

    const int cc_b   = ct * 16 + c16;    // this lane's B column (z-col in block)
    const int bxor   = (cc_b & 7) << 4;
    const int bbase  = cc_b * 2048;

    __syncthreads();

    for (int t = 0; t < tc; ++t) {
        const int s = base_step + t;
        const unsigned short* hr = hbuf + (size_t)(s & 1) * (BATCH * UNITS);
        unsigned short*       hw = hbuf + (size_t)((s + 1) & 1) * (BATCH * UNITS);

        // prefetch this step's xz early (independent of h)
        const float* xp = xz + ((size_t)t * BATCH + row_g) * ZCOLS + u0 + ui_g;
        float xv0 = xp[0];
        float xv1 = xp[UNITS];
        float xv2 = xp[2 * UNITS];
        float xv3 = xp[3 * UNITS];

        // h @ Wh for this wave's 16x16 tile, K=1024, two independent chains
        const unsigned short* ap = hr + (size_t)(rt * 16 + c16) * UNITS + kl;
        f32x4 ae = {0,0,0,0}, ao = {0,0,0,0};
        asm volatile("s_nop 1" : "+v"(ae), "+v"(ao));
        #pragma unroll 2
        for (int k2 = 0; k2 < 16; ++k2) {
            int kk = k2 * 2;
            u32x4 a0 = *reinterpret_cast<const u32x4*>(ap + kk * 32);
            u32x4 b0 = *reinterpret_cast<const u32x4*>(
                reinterpret_cast<char*>(whs) + (bbase + ((kk * 32 + kl) * 2 ^ bxor)));
            ae = mfma16x16x32_bf16(a0, b0, ae);
            u32x4 a1 = *reinterpret_cast<const u32x4*>(ap + (kk + 1) * 32);
            u32x4 b1 = *reinterpret_cast<const u32x4*>(
                reinterpret_cast<char*>(whs) + (bbase + (((kk + 1) * 32 + kl) * 2 ^ bxor)));
            ao = mfma16x16x32_bf16(a1, b1, ao);
        }
        asm volatile("s_nop 7\n\ts_nop 7\n\ts_nop 1" : "+v"(ae), "+v"(ao));
        {
            const int rowq = (lane >> 4) * 4;
            #pragma unroll
            for (int r = 0; r < 4; ++r)
                zbuf[rt * 16 + rowq + r][ct * 16 + c16] = ae[r] + ao[r];
        }
        __syncthreads();

        // gates: one (row, unit) per thread
        float z0 = zbuf[row_g][ui_g]      + xv0;
        float z1 = zbuf[row_g][16 + ui_g] + xv1;
        float z2 = zbuf[row_g][32 + ui_g] + xv2;
        float z3 = zbuf[row_g][48 + ui_g] + xv3;
        float ig = fsigmoid(z0);
        float fg = fsigmoid(z1);
        float gg = ftanh(z2);
        float og = fsigmoid(z3);
        creg = fg * creg + ig * gg;
        float hn = og * ftanh(creg);
        hw[(size_t)row_g * UNITS + u0 + ui_g] = f2bf(hn);
        if (s == T_STEPS - 1) out[(size_t)row_g * UNITS + u0 + ui_g] = hn;

        // grid barrier (skip on chunk-final step; kernel boundary syncs)
        if (t < tc - 1) {
            __syncthreads();                       // drains vmcnt: h stores in L2
            if (tid == 0) {
                __threadfence();                   // wbl2: h -> coherent point
                __hip_atomic_fetch_add(cnt, 1u, __ATOMIC_RELAXED, __HIP_MEMORY_SCOPE_AGENT);
                unsigned target = 64u * (unsigned)(base_round + t + 1);
                while (__hip_atomic_load(cnt, __ATOMIC_RELAXED, __HIP_MEMORY_SCOPE_AGENT) < target)
                    __builtin_amdgcn_s_sleep(2);
                __threadfence();                   // inv: L1/L2 so fresh h visible
            }
            __syncthreads();
        }
    }
    cbuf[(size_t)row_g * UNITS + u0 + ui_g] = creg;
}

// ---------------- launch ----------------

extern "C" void kernel_launch(void* const* d_in, const int* in_sizes, int n_in,
                              void* d_out, int out_size, void* d_ws, size_t ws_size,
                              hipStream_t stream) {
    const float* x    = (const float*)d_in[0];   // [64][512][512]
    const float* Wx   = (const float*)d_in[1];   // [512][4096]
    const float* Wh   = (const float*)d_in[2];   // [1024][4096]
    const float* bias = (const float*)d_in[3];   // [4096]

    char* ws = (char*)d_ws;
    unsigned short* WxT  = (unsigned short*)(ws);                            // 4 MB
    unsigned short* WhT  = (unsigned short*)(ws + (4u << 20));               // 8 MB
    unsigned short* hbuf = (unsigned short*)(ws + (12u << 20));              // 256 KB
    float*          cbuf = (float*)(ws + (12u << 20) + (256u << 10));        // 256 KB
    unsigned int*   cnt  = (unsigned int*)(ws + (12u << 20) + (512u << 10)); // 4 KB pad
    float*          xz   = (float*)(ws + (13u << 20));                       // T_c MB

    // pick largest time-chunk whose xz fits in the remaining workspace
    const size_t fixedB = 13u << 20;
    int tc = 1;
    const int cands[9] = {512, 256, 128, 64, 32, 16, 8, 4, 2};
    for (int i = 0; i < 9; ++i) {
        if (fixedB + (size_t)cands[i] * (1u << 20) <= ws_size) { tc = cands[i]; break; }
    }

    k_transpose_bf16<<<dim3(128, 16), dim3(32, 32), 0, stream>>>(Wx, WxT, 512, 4096);
    k_transpose_bf16<<<dim3(128, 32), dim3(32, 32), 0, stream>>>(Wh, WhT, 1024, 4096);
    k_init<<<512, 256, 0, stream>>>((unsigned int*)hbuf, cbuf, cnt);

    const int nch = T_STEPS / tc;
    for (int ci = 0; ci < nch; ++ci) {
        k_xproj<<<dim3(64, tc), 256, 0, stream>>>(x, WxT, bias, xz, ci * tc);
        k_lstm<<<64, 1024, 0, stream>>>(xz, WhT, hbuf, cbuf, (float*)d_out, cnt,
                                        ci * tc, tc, ci * (tc - 1));
    }
}

// Round 4
// 10858.377 us; speedup vs baseline: 1.0899x; 1.0899x over previous
//
#include <hip/hip_runtime.h>
#include <hip/hip_bf16.h>

// BasicLSTM: B=64, T=512, D=512, U=1024.  out = h_last [64][1024] f32.
// Per time-chunk (sized by ws_size): xz = x@Wx + b (f32), then persistent
// 64-block recurrent kernel. Per-step grid barrier = per-block release-store
// flags (128B apart) + 64-lane parallel poll (no atomic RMW).
// Wh lives in VGPRs (32x u32x4 per lane) for the whole recurrent kernel.

#define T_STEPS 512
#define BATCH   64
#define DIM     512
#define UNITS   1024
#define ZCOLS   4096

typedef float        f32x4 __attribute__((ext_vector_type(4)));
typedef unsigned int u32x4 __attribute__((ext_vector_type(4)));

__device__ __forceinline__ f32x4 mfma16x16x32_bf16(u32x4 a, u32x4 b, f32x4 c) {
    asm("v_mfma_f32_16x16x32_bf16 %0, %1, %2, %0" : "+v"(c) : "v"(a), "v"(b));
    return c;
}

__device__ __forceinline__ unsigned short f2bf(float f) {
    union { float f; unsigned u; } v; v.f = f;
    unsigned r = v.u + 0x7fffu + ((v.u >> 16) & 1u);   // RNE
    return (unsigned short)(r >> 16);
}

__device__ __forceinline__ float fsigmoid(float x) {
    return 1.0f / (1.0f + __expf(-x));
}
__device__ __forceinline__ float ftanh(float x) {
    return 1.0f - 2.0f / (__expf(2.0f * x) + 1.0f);
}

// pack 8 consecutive f32 -> 8 bf16 in a u32x4 (memory order)
__device__ __forceinline__ u32x4 pack8(const float* __restrict__ p) {
    float4 f0 = reinterpret_cast<const float4*>(p)[0];
    float4 f1 = reinterpret_cast<const float4*>(p)[1];
    u32x4 r;
    r.x = (unsigned)f2bf(f0.x) | ((unsigned)f2bf(f0.y) << 16);
    r.y = (unsigned)f2bf(f0.z) | ((unsigned)f2bf(f0.w) << 16);
    r.z = (unsigned)f2bf(f1.x) | ((unsigned)f2bf(f1.y) << 16);
    r.w = (unsigned)f2bf(f1.z) | ((unsigned)f2bf(f1.w) << 16);
    return r;
}

// ---------------- prep kernels ----------------

// in: f32 [K][N] row-major  ->  out: bf16 [N][K]
__global__ void k_transpose_bf16(const float* __restrict__ in, unsigned short* __restrict__ out,
                                 int K, int N) {
    __shared__ float tile[32][33];
    int n0 = blockIdx.x * 32, k0 = blockIdx.y * 32;
    int tx = threadIdx.x, ty = threadIdx.y;
    tile[ty][tx] = in[(size_t)(k0 + ty) * N + n0 + tx];
    __syncthreads();
    out[(size_t)(n0 + ty) * K + k0 + tx] = f2bf(tile[tx][ty]);
}

__global__ void k_init(unsigned int* __restrict__ hbuf_u32, float* __restrict__ cbuf,
                       unsigned int* __restrict__ flags) {
    int i = blockIdx.x * blockDim.x + threadIdx.x;       // 131072 threads
    if (i < 65536) hbuf_u32[i] = 0u;                     // 2*64*1024 bf16
    else cbuf[i - 65536] = 0.0f;                         // 64*1024 f32
    if (i < 2048) flags[i] = 0u;                         // 64 flags * 32 u32
}

// ---------------- phase 1: xz(chunk) = x_t @ Wx + b ----------------
// grid (8, T_c), 512 threads = 8 waves. Block: all 64 batch rows x 512 cols
// @ n0 = bx*512, K=512. x packed bf16 -> swizzled LDS once; B from global
// (XCD = n%8 keeps each 0.5MB B-slice L2-resident across t).
__global__ __launch_bounds__(512, 2) void k_xproj(
        const float* __restrict__ x,
        const unsigned short* __restrict__ WxT,   // [4096][512]
        const float* __restrict__ bias,
        float* __restrict__ xz,                   // [T_c][64][4096]
        int base) {
    const int tid  = threadIdx.x;
    const int lane = tid & 63;
    const int w    = tid >> 6;               // 0..7
    const int n0   = blockIdx.x * 512 + w * 64;
    const int t    = blockIdx.y;
    const int r16  = lane & 15;
    const int kl   = (lane >> 4) * 8;

    __shared__ __align__(16) unsigned short as_[64 * 512];   // 64 KB, XOR-swizzled

    // pack A: x[row, base+t, :] -> bf16 LDS
    for (int i = tid; i < 4096; i += 512) {
        int row = i >> 6, kc = i & 63;
        u32x4 v = pack8(x + ((size_t)row * T_STEPS + base + t) * DIM + kc * 8);
        int lb = (row * 1024 + kc * 16) ^ ((row & 7) << 4);
        *reinterpret_cast<u32x4*>(reinterpret_cast<char*>(as_) + lb) = v;
    }
    __syncthreads();

    const unsigned short* bp = WxT + (size_t)(n0 + r16) * DIM + kl;

    f32x4 acc[4][4] = {};
    asm volatile("s_nop 1" : "+v"(acc[0][0]), "+v"(acc[0][1]), "+v"(acc[0][2]), "+v"(acc[0][3]));
    asm volatile("s_nop 1" : "+v"(acc[1][0]), "+v"(acc[1][1]), "+v"(acc[1][2]), "+v"(acc[1][3]));
    asm volatile("s_nop 1" : "+v"(acc[2][0]), "+v"(acc[2][1]), "+v"(acc[2][2]), "+v"(acc[2][3]));
    asm volatile("s_nop 1" : "+v"(acc[3][0]), "+v"(acc[3][1]), "+v"(acc[3][2]), "+v"(acc[3][3]));

    #pragma unroll 2
    for (int kk = 0; kk < 16; ++kk) {
        u32x4 b0 = *reinterpret_cast<const u32x4*>(bp + kk * 32);
        u32x4 b1 = *reinterpret_cast<const u32x4*>(bp + 16 * DIM + kk * 32);
        u32x4 b2 = *reinterpret_cast<const u32x4*>(bp + 32 * DIM + kk * 32);
        u32x4 b3 = *reinterpret_cast<const u32x4*>(bp + 48 * DIM + kk * 32);
        u32x4 a[4];
        #pragma unroll
        for (int mt = 0; mt < 4; ++mt) {
            int row = mt * 16 + r16;
            int lb = (row * 1024 + (kk * 32 + kl) * 2) ^ ((row & 7) << 4);
            a[mt] = *reinterpret_cast<const u32x4*>(reinterpret_cast<const char*>(as_) + lb);
        }
        #pragma unroll
        for (int mt = 0; mt < 4; ++mt) {
            acc[mt][0] = mfma16x16x32_bf16(a[mt], b0, acc[mt][0]);
            acc[mt][1] = mfma16x16x32_bf16(a[mt], b1, acc[mt][1]);
            acc[mt][2] = mfma16x16x32_bf16(a[mt], b2, acc[mt][2]);
            acc[mt][3] = mfma16x16x32_bf16(a[mt], b3, acc[mt][3]);
        }
    }
    asm volatile("s_nop 7\n\ts_nop 7" : "+v"(acc[0][0]), "+v"(acc[0][1]), "+v"(acc[0][2]), "+v"(acc[0][3]));
    asm volatile("s_nop 7\n\ts_nop 7" : "+v"(acc[1][0]), "+v"(acc[1][1]), "+v"(acc[1][2]), "+v"(acc[1][3]));
    asm volatile("s_nop 7\n\ts_nop 7" : "+v"(acc[2][0]), "+v"(acc[2][1]), "+v"(acc[2][2]), "+v"(acc[2][3]));
    asm volatile("s_nop 7\n\ts_nop 7" : "+v"(acc[3][0]), "+v"(acc[3][1]), "+v"(acc[3][2]), "+v"(acc[3][3]));

    const int rowq = (lane >> 4) * 4;
    #pragma unroll
    for (int nt = 0; nt < 4; ++nt) {
        const int col = n0 + nt * 16 + r16;
        const float bv = bias[col];
        #pragma unroll
        for (int mt = 0; mt < 4; ++mt) {
            #pragma unroll
            for (int r = 0; r < 4; ++r) {
                int brow = mt * 16 + rowq + r;
                xz[((size_t)t * BATCH + brow) * ZCOLS + col] = acc[mt][nt][r] + bv;
            }
        }
    }
}

// ---------------- phase 2: recurrence ----------------
// 64 blocks x 512 threads (8 waves). Block owns 16 units (64 z-cols).
// Wave w: gate ct=w&3, m-half mh=w>>2; two 16x16 m-tiles sharing one
// B-column set held in 32 u32x4 VGPRs for the whole kernel.
__global__ __launch_bounds__(512, 2) void k_lstm(
        const float* __restrict__ xz,            // [T_c][64][4096], bias folded
        const unsigned short* __restrict__ WhT,  // [4096][1024]
        unsigned short* hbuf,                    // [2][64][1024] bf16
        float* __restrict__ cbuf,                // [64][1024] f32
        float* __restrict__ out,                 // [64][1024] f32
        unsigned int* flags,                     // [64] spaced 32 u32
        int base_step, int tc) {
    const int tid  = threadIdx.x;
    const int lane = tid & 63;
    const int w    = tid >> 6;          // 0..7
    const int ct   = w & 3;             // gate
    const int mh   = w >> 2;            // m half (0: rows 0-31, 1: rows 32-63)
    const int u0   = blockIdx.x * 16;
    const int c16  = lane & 15;
    const int kl   = (lane >> 4) * 8;

    __shared__ float zbuf[64][68];      // ~17 KB

    // B (Wh slice) in registers: col = WhT row ct*1024 + u0 + c16, k window kl
    u32x4 breg[32];
    {
        const unsigned short* wp = WhT + ((size_t)ct * UNITS + u0 + c16) * UNITS + kl;
        #pragma unroll
        for (int kk = 0; kk < 32; ++kk)
            breg[kk] = *reinterpret_cast<const u32x4*>(wp + kk * 32);
    }

    // gate-phase identity: two (row, unit) items per thread
    const int row0 = tid >> 4, ui0 = tid & 15;            // item 0
    const int row1 = (tid + 512) >> 4, ui1 = ui0;         // item 1
    float creg0 = cbuf[(size_t)row0 * UNITS + u0 + ui0];
    float creg1 = cbuf[(size_t)row1 * UNITS + u0 + ui1];

    for (int t = 0; t < tc; ++t) {
        const int s = base_step + t;
        const unsigned short* hr = hbuf + (size_t)(s & 1) * (BATCH * UNITS);
        unsigned short*       hw = hbuf + (size_t)((s + 1) & 1) * (BATCH * UNITS);

        // prefetch xz for gate phase (independent of h)
        const float* xp0 = xz + ((size_t)t * BATCH + row0) * ZCOLS + u0 + ui0;
        const float* xp1 = xz + ((size_t)t * BATCH + row1) * ZCOLS + u0 + ui1;
        float xv00 = xp0[0], xv01 = xp0[UNITS], xv02 = xp0[2 * UNITS], xv03 = xp0[3 * UNITS];
        float xv10 = xp1[0], xv11 = xp1[UNITS], xv12 = xp1[2 * UNITS], xv13 = xp1[3 * UNITS];

        // h @ Wh: two m-tiles, K=1024
        const unsigned short* a0p = hr + (size_t)(mh * 32 + c16) * UNITS + kl;
        const unsigned short* a1p = a0p + 16 * UNITS;
        f32x4 acc0 = {0, 0, 0, 0}, acc1 = {0, 0, 0, 0};
        asm volatile("s_nop 1" : "+v"(acc0), "+v"(acc1));
        #pragma unroll
        for (int kk = 0; kk < 32; ++kk) {
            u32x4 a0 = *reinterpret_cast<const u32x4*>(a0p + kk * 32);
            u32x4 a1 = *reinterpret_cast<const u32x4*>(a1p + kk * 32);
            acc0 = mfma16x16x32_bf16(a0, breg[kk], acc0);
            acc1 = mfma16x16x32_bf16(a1, breg[kk], acc1);
        }
        asm volatile("s_nop 7\n\ts_nop 7" : "+v"(acc0), "+v"(acc1));
        {
            const int rowq = (lane >> 4) * 4;
            #pragma unroll
            for (int r = 0; r < 4; ++r) {
                zbuf[mh * 32 + rowq + r][ct * 16 + c16]      = acc0[r];
                zbuf[mh * 32 + 16 + rowq + r][ct * 16 + c16] = acc1[r];
            }
        }
        __syncthreads();

        // gates: 512 threads x 2 (row, unit) items
        {
            float z0 = zbuf[row0][ui0] + xv00;
            float z1 = zbuf[row0][16 + ui0] + xv01;
            float z2 = zbuf[row0][32 + ui0] + xv02;
            float z3 = zbuf[row0][48 + ui0] + xv03;
            float ig = fsigmoid(z0), fg = fsigmoid(z1), gg = ftanh(z2), og = fsigmoid(z3);
            creg0 = fg * creg0 + ig * gg;
            float hn = og * ftanh(creg0);
            hw[(size_t)row0 * UNITS + u0 + ui0] = f2bf(hn);
            if (s == T_STEPS - 1) out[(size_t)row0 * UNITS + u0 + ui0] = hn;
        }
        {
            float z0 = zbuf[row1][ui1] + xv10;
            float z1 = zbuf[row1][16 + ui1] + xv11;
            float z2 = zbuf[row1][32 + ui1] + xv12;
            float z3 = zbuf[row1][48 + ui1] + xv13;
            float ig = fsigmoid(z0), fg = fsigmoid(z1), gg = ftanh(z2), og = fsigmoid(z3);
            creg1 = fg * creg1 + ig * gg;
            float hn = og * ftanh(creg1);
            hw[(size_t)row1 * UNITS + u0 + ui1] = f2bf(hn);
            if (s == T_STEPS - 1) out[(size_t)row1 * UNITS + u0 + ui1] = hn;
        }

        // grid barrier (skip on chunk-final step; kernel boundary syncs)
        if (t < tc - 1) {
            __syncthreads();   // all h stores issued + drained (vmcnt 0)
            if (w == 0) {
                if (lane == 0)
                    __hip_atomic_store(flags + (size_t)blockIdx.x * 32, (unsigned)(s + 1),
                                       __ATOMIC_RELEASE, __HIP_MEMORY_SCOPE_AGENT);
                const unsigned tgt = (unsigned)(s + 1);
                for (;;) {
                    unsigned v = __hip_atomic_load(flags + (size_t)lane * 32,
                                                   __ATOMIC_RELAXED, __HIP_MEMORY_SCOPE_AGENT);
                    if (__all((int)(v >= tgt))) break;
                    __builtin_amdgcn_s_sleep(1);
                }
                // acquire: invalidate stale cached h lines
                (void)__hip_atomic_load(flags, __ATOMIC_ACQUIRE, __HIP_MEMORY_SCOPE_AGENT);
            }
            __syncthreads();
        }
    }
    cbuf[(size_t)row0 * UNITS + u0 + ui0] = creg0;
    cbuf[(size_t)row1 * UNITS + u0 + ui1] = creg1;
}

// ---------------- launch ----------------

extern "C" void kernel_launch(void* const* d_in, const int* in_sizes, int n_in,
                              void* d_out, int out_size, void* d_ws, size_t ws_size,
                              hipStream_t stream) {
    const float* x    = (const float*)d_in[0];   // [64][512][512]
    const float* Wx   = (const float*)d_in[1];   // [512][4096]
    const float* Wh   = (const float*)d_in[2];   // [1024][4096]
    const float* bias = (const float*)d_in[3];   // [4096]

    char* ws = (char*)d_ws;
    unsigned short* WxT   = (unsigned short*)(ws);                            // 4 MB
    unsigned short* WhT   = (unsigned short*)(ws + (4u << 20));               // 8 MB
    unsigned short* hbuf  = (unsigned short*)(ws + (12u << 20));              // 256 KB
    float*          cbuf  = (float*)(ws + (12u << 20) + (256u << 10));        // 256 KB
    unsigned int*   flags = (unsigned int*)(ws + (12u << 20) + (512u << 10)); // 8 KB
    float*          xz    = (float*)(ws + (13u << 20));                       // T_c MB

    // pick largest time-chunk whose xz fits in the remaining workspace
    const size_t fixedB = 13u << 20;
    int tc = 1;
    const int cands[9] = {512, 256, 128, 64, 32, 16, 8, 4, 2};
    for (int i = 0; i < 9; ++i) {
        if (fixedB + (size_t)cands[i] * (1u << 20) <= ws_size) { tc = cands[i]; break; }
    }

    k_transpose_bf16<<<dim3(128, 16), dim3(32, 32), 0, stream>>>(Wx, WxT, 512, 4096);
    k_transpose_bf16<<<dim3(128, 32), dim3(32, 32), 0, stream>>>(Wh, WhT, 1024, 4096);
    k_init<<<512, 256, 0, stream>>>((unsigned int*)hbuf, cbuf, flags);

    const int nch = T_STEPS / tc;
    for (int ci = 0; ci < nch; ++ci) {
        k_xproj<<<dim3(8, tc), 512, 0, stream>>>(x, WxT, bias, xz, ci * tc);
        k_lstm<<<64, 512, 0, stream>>>(xz, WhT, hbuf, cbuf, (float*)d_out, flags,
                                       ci * tc, tc);
    }
}